// Round 13
// baseline (54.367 us; speedup 1.0000x reference)
//
#include <hip/hip_runtime.h>
#include <hip/hip_bf16.h>
#include <math.h>

// Problem sizes
#define Bn 4096
#define Dn 128
#define Cn 1000
#define Qn 65536

typedef __attribute__((ext_vector_type(8))) short short8v;  // bf16x8 MFMA frag
typedef __attribute__((ext_vector_type(4))) float f32x4;    // fp32x4 acc frag
typedef __attribute__((ext_vector_type(4))) float f4v;      // native float4
typedef unsigned short ushortT;

__device__ inline float waveAllMaxF(float v) {
    for (int o = 32; o; o >>= 1) v = fmaxf(v, __shfl_xor(v, o));
    return v;
}
__device__ inline float waveAllSumF(float v) {
    for (int o = 32; o; o >>= 1) v += __shfl_xor(v, o);
    return v;
}
__device__ inline float waveSumF(float v) {
    for (int o = 32; o; o >>= 1) v += __shfl_down(v, o);
    return v;
}
__device__ inline short f2bf(float x) {
    union { __hip_bfloat16 h; short s; } u;
    u.h = __float2bfloat16(x);
    return u.s;
}

// ================= K1: GEMM (no cls dependency) + cls =================
// 1280 blocks:
//   bid <  256 : cluster GEMM + row softmax, fp32 inputs converted in-register
//                (16 rows/block; compute-heavy -> scheduled FIRST)
//   else       : cls block (1024): 4 rows, one wave per row, MLP-8 loads
__global__ __launch_bounds__(256) void k_one(
    const float* __restrict__ logits, const float* __restrict__ plabel,
    const float* __restrict__ q, const float* __restrict__ proto,
    float* __restrict__ out_cls, int* __restrict__ labels,
    float* __restrict__ outC)
{
    __shared__ float red[16][4];
    int bid = blockIdx.x, t = threadIdx.x;

    if (bid < 256) {
        // ---- GEMM + softmax (in-register bf16 convert; round-7 verified) ----
        int lane = t & 63, w = t >> 6;
        int la = lane & 15, lk = lane >> 4;
        int row0 = bid * 16;

        f32x4 acc[16];
#pragma unroll
        for (int j = 0; j < 16; ++j) acc[j] = (f32x4){0.f, 0.f, 0.f, 0.f};

        const float* A0 = q + (long long)(row0 + la) * Dn;
#pragma unroll
        for (int kc = 0; kc < Dn; kc += 32) {
            short8v a;
            {
                f4v f0 = *(const f4v*)(A0 + kc + lk * 8);
                f4v f1 = *(const f4v*)(A0 + kc + lk * 8 + 4);
                a[0] = f2bf(f0.x); a[1] = f2bf(f0.y); a[2] = f2bf(f0.z); a[3] = f2bf(f0.w);
                a[4] = f2bf(f1.x); a[5] = f2bf(f1.y); a[6] = f2bf(f1.z); a[7] = f2bf(f1.w);
            }
#pragma unroll
            for (int j = 0; j < 16; ++j) {
                int prow = w * 256 + j * 16 + la;
                short8v b = {0, 0, 0, 0, 0, 0, 0, 0};
                if (prow < Cn) {
                    const float* Bp0 = proto + (long long)prow * Dn + kc + lk * 8;
                    f4v f0 = *(const f4v*)Bp0;
                    f4v f1 = *(const f4v*)(Bp0 + 4);
                    b[0] = f2bf(f0.x); b[1] = f2bf(f0.y); b[2] = f2bf(f0.z); b[3] = f2bf(f0.w);
                    b[4] = f2bf(f1.x); b[5] = f2bf(f1.y); b[6] = f2bf(f1.z); b[7] = f2bf(f1.w);
                }
                acc[j] = __builtin_amdgcn_mfma_f32_16x16x32_bf16(a, b, acc[j], 0, 0, 0);
            }
        }

        float m[4];
#pragma unroll
        for (int rg = 0; rg < 4; ++rg) {
            float v = -INFINITY;
#pragma unroll
            for (int j = 0; j < 16; ++j) {
                int col = w * 256 + j * 16 + la;
                if (col < Cn) v = fmaxf(v, acc[j][rg]);
            }
#pragma unroll
            for (int o = 1; o < 16; o <<= 1) v = fmaxf(v, __shfl_xor(v, o));
            m[rg] = v;
        }
        if (la == 0) {
#pragma unroll
            for (int rg = 0; rg < 4; ++rg) red[lk * 4 + rg][w] = m[rg];
        }
        __syncthreads();
#pragma unroll
        for (int rg = 0; rg < 4; ++rg) {
            int r = lk * 4 + rg;
            m[rg] = fmaxf(fmaxf(red[r][0], red[r][1]), fmaxf(red[r][2], red[r][3]));
        }
        __syncthreads();

        float s[4];
#pragma unroll
        for (int rg = 0; rg < 4; ++rg) {
            float v = 0.f;
#pragma unroll
            for (int j = 0; j < 16; ++j) {
                int col = w * 256 + j * 16 + la;
                float e = (col < Cn) ? expf(acc[j][rg] - m[rg]) : 0.f;
                acc[j][rg] = e;
                v += e;
            }
#pragma unroll
            for (int o = 1; o < 16; o <<= 1) v += __shfl_xor(v, o);
            s[rg] = v;
        }
        if (la == 0) {
#pragma unroll
            for (int rg = 0; rg < 4; ++rg) red[lk * 4 + rg][w] = s[rg];
        }
        __syncthreads();
#pragma unroll
        for (int rg = 0; rg < 4; ++rg) {
            int r = lk * 4 + rg;
            s[rg] = 1.f / (red[r][0] + red[r][1] + red[r][2] + red[r][3]);
        }

#pragma unroll
        for (int j = 0; j < 16; ++j) {
            int col = w * 256 + j * 16 + la;
            if (col < Cn) {
                int rowb = row0 + lk * 4;
#pragma unroll
                for (int rg = 0; rg < 4; ++rg)
                    outC[(long long)(rowb + rg) * Cn + col] = acc[j][rg] * s[rg];
            }
        }
        return;
    }

    // ---- cls block: 4 rows, one wave per row, all loads issued up front ----
    int g = bid - 256;
    int lane = t & 63, wid = t >> 6;
    int row = g * 4 + wid;
    const float* x  = logits + (long long)row * Cn;
    const float* pl = plabel + (long long)row * Cn;

    f4v lv[4], pv[4];
#pragma unroll
    for (int j = 0; j < 4; ++j) {
        int f4i = lane + j * 64;
        if (f4i < 250) {
            lv[j] = *(const f4v*)(x + f4i * 4);
            pv[j] = *(const f4v*)(pl + f4i * 4);
        } else {
            lv[j] = (f4v){-INFINITY, -INFINITY, -INFINITY, -INFINITY};
            pv[j] = (f4v){0.f, 0.f, 0.f, 0.f};
        }
    }

    float mx = -INFINITY;
#pragma unroll
    for (int j = 0; j < 4; ++j)
        mx = fmaxf(mx, fmaxf(fmaxf(lv[j].x, lv[j].y), fmaxf(lv[j].z, lv[j].w)));
    mx = waveAllMaxF(mx);

    float vv[16];
    float ssum = 0.f;
#pragma unroll
    for (int j = 0; j < 4; ++j) {
        vv[j * 4 + 0] = expf(lv[j].x - mx);
        vv[j * 4 + 1] = expf(lv[j].y - mx);
        vv[j * 4 + 2] = expf(lv[j].z - mx);
        vv[j * 4 + 3] = expf(lv[j].w - mx);
        ssum += vv[j * 4 + 0] + vv[j * 4 + 1] + vv[j * 4 + 2] + vv[j * 4 + 3];
    }
    ssum = waveAllSumF(ssum);
    float inv = 1.f / ssum;

    float bv = -INFINITY; int bi = Cn;
#pragma unroll
    for (int j = 0; j < 4; ++j) {
        int f4i = lane + j * 64;
        if (f4i < 250) {
            float o0 = vv[j * 4 + 0] * inv, o1 = vv[j * 4 + 1] * inv;
            float o2 = vv[j * 4 + 2] * inv, o3 = vv[j * 4 + 3] * inv;
            *((f4v*)(out_cls + (long long)row * Cn) + f4i) = (f4v){o0, o1, o2, o3};
            float pr[4] = {o0 * pv[j].x, o1 * pv[j].y, o2 * pv[j].z, o3 * pv[j].w};
#pragma unroll
            for (int jj = 0; jj < 4; ++jj) {
                if (pr[jj] > bv) { bv = pr[jj]; bi = f4i * 4 + jj; }
            }
        }
    }
    for (int o = 32; o; o >>= 1) {
        float ov = __shfl_xor(bv, o);
        int   oi = __shfl_xor(bi, o);
        if (ov > bv || (ov == bv && oi < bi)) { bv = ov; bi = oi; }
    }
    if (lane == 0) labels[row] = bi;
}

// ================= K2: proto + tail + copy (compute-first) =================
// 3849 blocks:
//   bid < 1000 : prototype update + L2 norm (ONE class/block, 16.4 KB LDS,
//                all-4-wave ballot scan, popcount-ordered extraction)
//   bid < 1545 : cont_labels / new_queue_pseudo / new_ptr tail (545)
//   bid < 1801 : feat q|k tile (256, branch-free)
//   else       : queue tile -> out_feat + out_queue (2048, MLP-4)
__global__ __launch_bounds__(256) void k_two(
    const float* __restrict__ proto, const float* __restrict__ q,
    const float* __restrict__ kk, const float* __restrict__ queue,
    const int* __restrict__ lbl, const float* __restrict__ qps,
    const int* __restrict__ ptrp,
    float* __restrict__ outp,
    float* __restrict__ out_lab, float* __restrict__ out_qps,
    float* __restrict__ out_ptr,
    float* __restrict__ out_feat, float* __restrict__ out_queue)
{
    __shared__ ushortT slab[Bn];        // 8 KB
    __shared__ ushortT lists[4][1024];  // 8 KB
    __shared__ int cnts[4];
    __shared__ float shh[2];
    int bid = blockIdx.x, t = threadIdx.x;

    if (bid < 1000) {
        // ---- prototype: ordered per-class list via ballot+popcount ----
        int c = bid;
#pragma unroll
        for (int u = 0; u < 4; ++u) {
            int4 v = ((const int4*)lbl)[u * 256 + t];
            int base = (u * 256 + t) * 4;
            slab[base + 0] = (ushortT)v.x; slab[base + 1] = (ushortT)v.y;
            slab[base + 2] = (ushortT)v.z; slab[base + 3] = (ushortT)v.w;
        }
        __syncthreads();

        int w = t >> 6, ln = t & 63;
        int cnt = 0;
        for (int jj = 0; jj < 16; ++jj) {
            int j = w * 1024 + jj * 64 + ln;
            bool mt = (slab[j] == (ushortT)c);
            unsigned long long mask = __ballot(mt);
            if (mt) {
                int pos = cnt + __popcll(mask & ((1ull << ln) - 1ull));
                lists[w][pos] = (ushortT)j;
            }
            cnt += (int)__popcll(mask);
        }
        if (ln == 0) cnts[w] = cnt;
        __syncthreads();

        float acc = 0.f;
        if (t < Dn) {
            int n = cnts[0] + cnts[1] + cnts[2] + cnts[3];
            acc = proto[(long long)c * Dn + t] * __powf(0.99f, (float)n);
            int base = 0;
#pragma unroll 1
            for (int w2 = 0; w2 < 4; ++w2) {
                int cw = cnts[w2];
                for (int mi = 0; mi < cw; ++mi) {
                    int r = lists[w2][mi];
                    acc += 0.01f * __powf(0.99f, (float)(n - 1 - (base + mi)))
                         * q[(long long)r * Dn + t];
                }
                base += cw;
            }
        }
        float ss = waveSumF(acc * acc);
        if ((t & 63) == 0 && t < Dn) shh[t >> 6] = ss;
        __syncthreads();
        if (t < Dn) {
            float nrm = sqrtf(shh[0] + shh[1]);
            outp[(long long)c * Dn + t] = acc / fmaxf(nrm, 1e-12f);
        }
        return;
    }

    if (bid < 1545) {
        // ---- labels / queue_pseudo / ptr tail ----
        int gid = (bid - 1000) * 256 + t;
        const int NL = 2 * Bn + Qn;   // 73728
        int p = *ptrp;
        int pc = p < 0 ? 0 : (p > Qn - Bn ? Qn - Bn : p);
        if (gid < NL) {
            float v;
            if (gid < Bn)          v = (float)lbl[gid];
            else if (gid < 2 * Bn) v = (float)lbl[gid - Bn];
            else                   v = qps[gid - 2 * Bn];
            out_lab[gid] = v;
        }
        int j = gid - NL;
        if (j >= 0 && j < Qn) {
            unsigned rr = (unsigned)(j - pc);
            out_qps[j] = (rr < (unsigned)Bn) ? (float)lbl[rr] : qps[j];
        }
        if (gid == NL + Qn) out_ptr[0] = (float)((p + Bn) % Qn);
        return;
    }

    if (bid < 1801) {
        // ---- feat q|k tile: 4096 floats, entirely one source ----
        int fb = bid - 1545;
        const float* src = (fb < 128) ? q : kk;
        long long sb = (long long)(fb & 127) * 4096;
        long long db = (long long)fb * 4096;
        f4v v[4];
#pragma unroll
        for (int u = 0; u < 4; ++u)
            v[u] = *(const f4v*)(src + sb + (u * 256 + t) * 4);
#pragma unroll
        for (int u = 0; u < 4; ++u)
            *(f4v*)(out_feat + db + (u * 256 + t) * 4) = v[u];
        return;
    }

    {
        // ---- queue tile: 4096 floats; all loads first, then stores ----
        int cb = bid - 1801;
        int p = *ptrp;
        int pc = p < 0 ? 0 : (p > Qn - Bn ? Qn - Bn : p);
        long long base = (long long)cb * 4096;
        const long long FB = 2LL * Bn * Dn;      // 1048576
        f4v v[4];
#pragma unroll
        for (int u = 0; u < 4; ++u)
            v[u] = *(const f4v*)(queue + base + (u * 256 + t) * 4);
#pragma unroll
        for (int u = 0; u < 4; ++u)
            *(f4v*)(out_feat + FB + base + (u * 256 + t) * 4) = v[u];
#pragma unroll
        for (int u = 0; u < 4; ++u) {
            long long foff = base + (u * 256 + t) * 4;
            int row = (int)(foff >> 7);
            unsigned rr = (unsigned)(row - pc);
            f4v wv = v[u];
            if (rr < (unsigned)Bn) wv = *(const f4v*)(kk + (long long)rr * Dn + (foff & 127));
            *(f4v*)(out_queue + foff) = wv;
        }
    }
}

// ---------------- host ----------------
extern "C" void kernel_launch(void* const* d_in, const int* in_sizes, int n_in,
                              void* d_out, int out_size, void* d_ws, size_t ws_size,
                              hipStream_t stream)
{
    const float* q     = (const float*)d_in[0];
    const float* kk    = (const float*)d_in[1];
    const float* cl    = (const float*)d_in[2];
    const float* plab  = (const float*)d_in[3];
    const float* proto = (const float*)d_in[4];
    const float* queue = (const float*)d_in[5];
    const float* qps   = (const float*)d_in[6];
    const int*   ptrp  = (const int*)d_in[7];

    float* out = (float*)d_out;
    // output layout (flat float offsets, return order)
    const long long O_CLU  = 4096000;     // cluster_out
    const long long O_FEAT = 8192000;     // cont_features
    const long long O_LAB  = 17629184;    // cont_labels
    const long long O_PROT = 17702912;    // new_prototypes
    const long long O_QUE  = 17830912;    // new_queue
    const long long O_QPS  = 26219520;    // new_queue_pseudo
    const long long O_PTR  = 26285056;    // new_ptr

    char* ws = (char*)d_ws;
    int* lbl = (int*)(ws + 0);            // [4096]

    k_one<<<1280, 256, 0, stream>>>(cl, plab, q, proto, out, lbl, out + O_CLU);
    k_two<<<3849, 256, 0, stream>>>(proto, q, kk, queue, lbl, qps, ptrp,
                                    out + O_PROT,
                                    out + O_LAB, out + O_QPS, out + O_PTR,
                                    out + O_FEAT, out + O_QUE);
}

// Round 14
// 47.759 us; speedup vs baseline: 1.1384x; 1.1384x over previous
//
#include <hip/hip_runtime.h>
#include <hip/hip_bf16.h>
#include <math.h>

// Problem sizes
#define Bn 4096
#define Dn 128
#define Cn 1000
#define Qn 65536

typedef __attribute__((ext_vector_type(8))) short short8v;  // bf16x8 MFMA frag
typedef __attribute__((ext_vector_type(4))) short short4v;  // bf16x4 store
typedef __attribute__((ext_vector_type(4))) float f32x4;    // fp32x4 acc frag
typedef __attribute__((ext_vector_type(4))) float f4v;      // native float4

__device__ inline float waveAllMaxF(float v) {
    for (int o = 32; o; o >>= 1) v = fmaxf(v, __shfl_xor(v, o));
    return v;
}
__device__ inline float waveAllSumF(float v) {
    for (int o = 32; o; o >>= 1) v += __shfl_xor(v, o);
    return v;
}
__device__ inline float waveSumF(float v) {
    for (int o = 32; o; o >>= 1) v += __shfl_down(v, o);
    return v;
}
__device__ inline short f2bf(float x) {
    union { __hip_bfloat16 h; short s; } u;
    u.h = __float2bfloat16(x);
    return u.s;
}

// ================= K1: cls only (R11 verbatim) =================
// 1024 blocks: 4 rows each, one wave per row; logits AND plabel loads issued
// together up front (8 outstanding 16B loads/lane) + bf16-convert fold.
__global__ __launch_bounds__(256) void k_cls(
    const float* __restrict__ logits, const float* __restrict__ plabel,
    const float* __restrict__ q, const float* __restrict__ proto,
    float* __restrict__ out_cls, int* __restrict__ labels,
    __hip_bfloat16* __restrict__ qb, __hip_bfloat16* __restrict__ pb)
{
    int g = blockIdx.x, t = threadIdx.x;

    if (t < 160) {
        int idx4 = g * 160 + t;
        if (idx4 < 131072) {                      // q: 524288/4
            f4v v = *(const f4v*)(q + (long long)idx4 * 4);
            short4v o = {f2bf(v.x), f2bf(v.y), f2bf(v.z), f2bf(v.w)};
            *(short4v*)((short*)qb + (long long)idx4 * 4) = o;
        } else {
            int j4 = idx4 - 131072;               // proto: 32768 float4 slots (padded)
            short4v o = {0, 0, 0, 0};
            if (j4 < 32000) {
                f4v v = *(const f4v*)(proto + (long long)j4 * 4);
                o = (short4v){f2bf(v.x), f2bf(v.y), f2bf(v.z), f2bf(v.w)};
            }
            *(short4v*)((short*)pb + (long long)j4 * 4) = o;
        }
    }

    int lane = t & 63, wid = t >> 6;
    int row = g * 4 + wid;
    const float* x  = logits + (long long)row * Cn;
    const float* pl = plabel + (long long)row * Cn;

    f4v lv[4], pv[4];
#pragma unroll
    for (int j = 0; j < 4; ++j) {                 // issue ALL loads up front (MLP=8)
        int f4i = lane + j * 64;
        if (f4i < 250) {
            lv[j] = *(const f4v*)(x + f4i * 4);
            pv[j] = *(const f4v*)(pl + f4i * 4);
        } else {
            lv[j] = (f4v){-INFINITY, -INFINITY, -INFINITY, -INFINITY};
            pv[j] = (f4v){0.f, 0.f, 0.f, 0.f};
        }
    }

    float mx = -INFINITY;
#pragma unroll
    for (int j = 0; j < 4; ++j)
        mx = fmaxf(mx, fmaxf(fmaxf(lv[j].x, lv[j].y), fmaxf(lv[j].z, lv[j].w)));
    mx = waveAllMaxF(mx);

    float vv[16];
    float ssum = 0.f;
#pragma unroll
    for (int j = 0; j < 4; ++j) {
        vv[j * 4 + 0] = expf(lv[j].x - mx);
        vv[j * 4 + 1] = expf(lv[j].y - mx);
        vv[j * 4 + 2] = expf(lv[j].z - mx);
        vv[j * 4 + 3] = expf(lv[j].w - mx);
        ssum += vv[j * 4 + 0] + vv[j * 4 + 1] + vv[j * 4 + 2] + vv[j * 4 + 3];
    }
    ssum = waveAllSumF(ssum);
    float inv = 1.f / ssum;

    float bv = -INFINITY; int bi = Cn;
#pragma unroll
    for (int j = 0; j < 4; ++j) {
        int f4i = lane + j * 64;
        if (f4i < 250) {
            float o0 = vv[j * 4 + 0] * inv, o1 = vv[j * 4 + 1] * inv;
            float o2 = vv[j * 4 + 2] * inv, o3 = vv[j * 4 + 3] * inv;
            *((f4v*)(out_cls + (long long)row * Cn) + f4i) = (f4v){o0, o1, o2, o3};
            float pr[4] = {o0 * pv[j].x, o1 * pv[j].y, o2 * pv[j].z, o3 * pv[j].w};
#pragma unroll
            for (int jj = 0; jj < 4; ++jj) {
                if (pr[jj] > bv) { bv = pr[jj]; bi = f4i * 4 + jj; }
            }
        }
    }
    for (int o = 32; o; o >>= 1) {
        float ov = __shfl_xor(bv, o);
        int   oi = __shfl_xor(bi, o);
        if (ov > bv || (ov == bv && oi < bi)) { bv = ov; bi = oi; }
    }
    if (lane == 0) labels[row] = bi;
}

// ================= K2: compute-first union (R11 structure, tiled copy) =================
// 3605 blocks:
//   bid <  256 : cluster GEMM + row softmax (16 rows/block, bf16 qb/pb)
//   bid <  756 : prototype EMA + L2 norm (R11/R9 LDS-staged, 2 classes/block)
//   bid < 1301 : cont_labels / new_queue_pseudo / new_ptr tail (545 blocks)
//   bid < 1557 : feat q|k tile (256, branch-free, MLP-4)
//   else       : queue tile -> out_feat + out_queue (2048, loads-first MLP-4)
__global__ __launch_bounds__(256) void k_rest(
    const __hip_bfloat16* __restrict__ qb, const __hip_bfloat16* __restrict__ pbuf,
    const float* __restrict__ proto, const float* __restrict__ q,
    const float* __restrict__ kk, const float* __restrict__ queue,
    const int* __restrict__ lbl, const float* __restrict__ qps,
    const int* __restrict__ ptrp,
    float* __restrict__ outC, float* __restrict__ outp,
    float* __restrict__ out_lab, float* __restrict__ out_qps,
    float* __restrict__ out_ptr,
    float* __restrict__ out_feat, float* __restrict__ out_queue)
{
    __shared__ __align__(16) char smem[32800];
    int bid = blockIdx.x, t = threadIdx.x;

    if (bid < 256) {
        // ---- GEMM + softmax (R11 verbatim) ----
        float (*red)[4] = (float (*)[4])smem;   // [16][4]
        int lane = t & 63, w = t >> 6;
        int la = lane & 15, lk = lane >> 4;
        int row0 = bid * 16;

        f32x4 acc[16];
#pragma unroll
        for (int j = 0; j < 16; ++j) acc[j] = (f32x4){0.f, 0.f, 0.f, 0.f};

        const short* A = (const short*)qb + (long long)(row0 + la) * Dn;
        const short* Bp = (const short*)pbuf;
#pragma unroll
        for (int kc = 0; kc < Dn; kc += 32) {
            short8v a = *(const short8v*)(A + kc + lk * 8);
#pragma unroll
            for (int j = 0; j < 16; ++j) {
                int prow = w * 256 + j * 16 + la;
                short8v b = *(const short8v*)(Bp + (long long)prow * Dn + kc + lk * 8);
                acc[j] = __builtin_amdgcn_mfma_f32_16x16x32_bf16(a, b, acc[j], 0, 0, 0);
            }
        }

        float m[4];
#pragma unroll
        for (int rg = 0; rg < 4; ++rg) {
            float v = -INFINITY;
#pragma unroll
            for (int j = 0; j < 16; ++j) {
                int col = w * 256 + j * 16 + la;
                if (col < Cn) v = fmaxf(v, acc[j][rg]);
            }
#pragma unroll
            for (int o = 1; o < 16; o <<= 1) v = fmaxf(v, __shfl_xor(v, o));
            m[rg] = v;
        }
        if (la == 0) {
#pragma unroll
            for (int rg = 0; rg < 4; ++rg) red[lk * 4 + rg][w] = m[rg];
        }
        __syncthreads();
#pragma unroll
        for (int rg = 0; rg < 4; ++rg) {
            int r = lk * 4 + rg;
            m[rg] = fmaxf(fmaxf(red[r][0], red[r][1]), fmaxf(red[r][2], red[r][3]));
        }
        __syncthreads();

        float s[4];
#pragma unroll
        for (int rg = 0; rg < 4; ++rg) {
            float v = 0.f;
#pragma unroll
            for (int j = 0; j < 16; ++j) {
                int col = w * 256 + j * 16 + la;
                float e = (col < Cn) ? expf(acc[j][rg] - m[rg]) : 0.f;
                acc[j][rg] = e;
                v += e;
            }
#pragma unroll
            for (int o = 1; o < 16; o <<= 1) v += __shfl_xor(v, o);
            s[rg] = v;
        }
        if (la == 0) {
#pragma unroll
            for (int rg = 0; rg < 4; ++rg) red[lk * 4 + rg][w] = s[rg];
        }
        __syncthreads();
#pragma unroll
        for (int rg = 0; rg < 4; ++rg) {
            int r = lk * 4 + rg;
            s[rg] = 1.f / (red[r][0] + red[r][1] + red[r][2] + red[r][3]);
        }

#pragma unroll
        for (int j = 0; j < 16; ++j) {
            int col = w * 256 + j * 16 + la;
            if (col < Cn) {
                int rowb = row0 + lk * 4;
#pragma unroll
                for (int rg = 0; rg < 4; ++rg)
                    outC[(long long)(rowb + rg) * Cn + col] = acc[j][rg] * s[rg];
            }
        }
    } else if (bid < 756) {
        // ---- prototype EMA + L2 norm, 2 classes per block (R11 verbatim) ----
        int* sl = (int*)smem;                                    // [4096]
        unsigned short* list0 = (unsigned short*)(smem + 16384); // [4096]
        unsigned short* list1 = list0 + 4096;                    // [4096]
        int* nm = (int*)(smem + 32768);                          // [2]
        float* shh = (float*)(smem + 32776);                     // [4]

        int h = t >> 7, tt = t & 127;
        int c = (bid - 256) * 2 + h;                             // < 1000 always

#pragma unroll
        for (int u = 0; u < 4; ++u) {
            int base = (u * 256 + t) * 4;
            *(int4*)(sl + base) = *(const int4*)(lbl + base);
        }
        if (t == 0)   nm[0] = 0;
        if (t == 128) nm[1] = 0;
        __syncthreads();

        int wv = t >> 6;
        if ((wv & 1) == 0) {            // waves 0 and 2 scan for their half's class
            int hh = wv >> 1;
            int ln = t & 63;
            int cc = (bid - 256) * 2 + hh;
            unsigned short* lst = hh ? list1 : list0;
            int n = 0;
            for (int jj = 0; jj < Bn / 64; ++jj) {
                unsigned long long mask = __ballot(sl[jj * 64 + ln] == cc);
                if (ln == 0) {
                    while (mask) {
                        int b = __builtin_ctzll(mask);
                        lst[n++] = (unsigned short)(jj * 64 + b);
                        mask &= mask - 1;
                    }
                }
            }
            if (ln == 0) nm[hh] = n;
        }
        __syncthreads();

        int n = nm[h];
        unsigned short* lst = h ? list1 : list0;
        float acc = proto[(long long)c * Dn + tt];
        for (int mi = 0; mi < n; ++mi)
            acc = 0.99f * acc + 0.01f * q[(long long)lst[mi] * Dn + tt];

        float ss = waveSumF(acc * acc);
        if ((t & 63) == 0) shh[t >> 6] = ss;
        __syncthreads();
        float nn = sqrtf(shh[h * 2] + shh[h * 2 + 1]);
        outp[(long long)c * Dn + tt] = acc / fmaxf(nn, 1e-12f);
    } else if (bid < 1301) {
        // ---- labels / queue_pseudo / ptr tail (545 blocks, R11 verbatim) ----
        int gid = (bid - 756) * 256 + t;
        const int NL = 2 * Bn + Qn;   // 73728
        int p = *ptrp;
        int pc = p < 0 ? 0 : (p > Qn - Bn ? Qn - Bn : p);
        if (gid < NL) {
            float v;
            if (gid < Bn)          v = (float)lbl[gid];
            else if (gid < 2 * Bn) v = (float)lbl[gid - Bn];
            else                   v = qps[gid - 2 * Bn];
            out_lab[gid] = v;
        }
        int j = gid - NL;
        if (j >= 0 && j < Qn) {
            unsigned rr = (unsigned)(j - pc);
            out_qps[j] = (rr < (unsigned)Bn) ? (float)lbl[rr] : qps[j];
        }
        if (gid == NL + Qn) out_ptr[0] = (float)((p + Bn) % Qn);
    } else if (bid < 1557) {
        // ---- feat q|k tile: 4096 floats, entirely one source (MLP-4) ----
        int fb = bid - 1301;
        const float* src = (fb < 128) ? q : kk;
        long long sb = (long long)(fb & 127) * 4096;
        long long db = (long long)fb * 4096;
        f4v v[4];
#pragma unroll
        for (int u = 0; u < 4; ++u)
            v[u] = *(const f4v*)(src + sb + (u * 256 + t) * 4);
#pragma unroll
        for (int u = 0; u < 4; ++u)
            *(f4v*)(out_feat + db + (u * 256 + t) * 4) = v[u];
    } else {
        // ---- queue tile: 4096 floats; all loads first, then stores ----
        int cb = bid - 1557;
        int p = *ptrp;
        int pc = p < 0 ? 0 : (p > Qn - Bn ? Qn - Bn : p);
        long long base = (long long)cb * 4096;
        const long long FB = 2LL * Bn * Dn;      // 1048576
        f4v v[4];
#pragma unroll
        for (int u = 0; u < 4; ++u)
            v[u] = *(const f4v*)(queue + base + (u * 256 + t) * 4);
#pragma unroll
        for (int u = 0; u < 4; ++u)
            *(f4v*)(out_feat + FB + base + (u * 256 + t) * 4) = v[u];
#pragma unroll
        for (int u = 0; u < 4; ++u) {
            long long foff = base + (u * 256 + t) * 4;
            int row = (int)(foff >> 7);
            unsigned rr = (unsigned)(row - pc);
            f4v wv = v[u];
            if (rr < (unsigned)Bn) wv = *(const f4v*)(kk + (long long)rr * Dn + (foff & 127));
            *(f4v*)(out_queue + foff) = wv;
        }
    }
}

// ---------------- host ----------------
extern "C" void kernel_launch(void* const* d_in, const int* in_sizes, int n_in,
                              void* d_out, int out_size, void* d_ws, size_t ws_size,
                              hipStream_t stream)
{
    const float* q     = (const float*)d_in[0];
    const float* kk    = (const float*)d_in[1];
    const float* cl    = (const float*)d_in[2];
    const float* plab  = (const float*)d_in[3];
    const float* proto = (const float*)d_in[4];
    const float* queue = (const float*)d_in[5];
    const float* qps   = (const float*)d_in[6];
    const int*   ptrp  = (const int*)d_in[7];

    float* out = (float*)d_out;
    // output layout (flat float offsets, return order)
    const long long O_CLU  = 4096000;     // cluster_out
    const long long O_FEAT = 8192000;     // cont_features
    const long long O_LAB  = 17629184;    // cont_labels
    const long long O_PROT = 17702912;    // new_prototypes
    const long long O_QUE  = 17830912;    // new_queue
    const long long O_QPS  = 26219520;    // new_queue_pseudo
    const long long O_PTR  = 26285056;    // new_ptr

    char* ws = (char*)d_ws;
    int*   lbl = (int*)(ws + 0);                           // [4096]
    __hip_bfloat16* qb = (__hip_bfloat16*)(ws + 1048576);  // [4096*128] bf16
    __hip_bfloat16* pb = (__hip_bfloat16*)(ws + 2097152);  // [1024*128] bf16 (padded)

    k_cls<<<1024, 256, 0, stream>>>(cl, plab, q, proto, out, lbl, qb, pb);
    k_rest<<<3605, 256, 0, stream>>>(qb, pb, proto, q, kk, queue, lbl, qps, ptrp,
                                     out + O_CLU, out + O_PROT,
                                     out + O_LAB, out + O_QPS, out + O_PTR,
                                     out + O_FEAT, out + O_QUE);
}